// Round 15
// baseline (561.814 us; speedup 1.0000x reference)
//
#include <hip/hip_runtime.h>
#include <math.h>

typedef __attribute__((ext_vector_type(8))) short bf16x8;
typedef __attribute__((ext_vector_type(4))) float f32x4;
typedef __attribute__((ext_vector_type(4))) float f4v;

#define BS   64
#define DIM  512
#define SRC  400
#define TDEC 100
#define NEMB 50257
#define K3   1536   // 3*DIM

// workspace float offsets
#define WS_Q     0          // [2][64][512]
#define WS_EENC  65536      // [64][400]  raw E
#define WS_EDEC  91136      // [64][100]  raw E
#define WS_CENC  97536      // [64][512]  unnormalized C (atomic)
#define WS_CDEC  130304     // [64][512]
#define WS_ESUM  163072     // [2][64]
#define WS_PSW   163200     // [64]
#define WS_SMAX  163264     // [64][4] partial max
#define WS_SSUM  163520     // [64][4] partial sum
#define WS_WPT   163776     // 96 chunks x 16KB, FRAGMENT-MAJOR bf16 (1.5MB)
#define WS_CCF   556992     // 24 tiles x 8KB, fragment-major c_cat bf16 (192KB)
#define WS_ZBEG  WS_CENC
#define WS_ZCNT  (WS_WPT - WS_CENC)

__device__ __forceinline__ ushort f2bf(float x) {
    union { float f; unsigned u; } v; v.f = x;
    unsigned r = (v.u + 0x7FFFu + ((v.u >> 16) & 1u)) >> 16;
    return (ushort)r;
}
__device__ __forceinline__ float bfdec(unsigned u16) {
    return __uint_as_float(u16 << 16);
}
__device__ __forceinline__ bf16x8 pack8v(f4v a, f4v b) {
    union { ushort us[8]; bf16x8 v; } p;
    p.us[0] = f2bf(a.x); p.us[1] = f2bf(a.y); p.us[2] = f2bf(a.z); p.us[3] = f2bf(a.w);
    p.us[4] = f2bf(b.x); p.us[5] = f2bf(b.y); p.us[6] = f2bf(b.z); p.us[7] = f2bf(b.w);
    return p.v;
}
// Pade [3/2] tanh: |x| <~ 0.06 here -> abs err < 1e-9.
__device__ __forceinline__ float pade_tanh(float x) {
    const float x2 = x * x;
    const float num = x * fmaf(x2, 1.0f / 15.0f, 1.0f);
    const float den = fmaf(x2, 0.4f, 1.0f);
    return num * __frcp_rn(den);
}
__device__ __forceinline__ void gl2lds16(const void* g, void* l) {
    __builtin_amdgcn_global_load_lds(
        (const __attribute__((address_space(1))) unsigned int*)g,
        (__attribute__((address_space(3))) unsigned int*)l, 16, 0, 0);
}

// ------- merged prep: zero accumulators; blocks [0,32) q; [32,128) WpT chunks ---
__global__ __launch_bounds__(256) void k_prep(const float* __restrict__ h_t,
                                              const float* __restrict__ Wenc,
                                              const float* __restrict__ Wdec,
                                              const float* __restrict__ Wp,
                                              float* __restrict__ ws) {
    __shared__ float sh[128 * 68];
    const int tid = threadIdx.x;
    // zero the atomic accumulator region (runs in every block, before k_attn)
    for (int i = blockIdx.x * 256 + tid; i < WS_ZCNT; i += 128 * 256)
        ws[WS_ZBEG + i] = 0.f;
    if (blockIdx.x < 32) {
        const int which = blockIdx.x >> 4;
        const int c0 = (blockIdx.x & 15) * 32;
        const float* W = which ? Wdec : Wenc;
        float* q = ws + WS_Q + which * (BS * DIM);
        float* hS = sh;                 // [64 b][65]
        float* WSm = sh + 64 * 65;      // [64 k][33]
        const int c = tid & 31, bg = tid >> 5;
        float acc[8] = {0.f, 0.f, 0.f, 0.f, 0.f, 0.f, 0.f, 0.f};
        for (int kc = 0; kc < 8; ++kc) {
            __syncthreads();
            #pragma unroll
            for (int r = 0; r < 16; ++r) {
                const int idx = r * 256 + tid;
                const int b = idx >> 6, k = idx & 63;
                hS[b * 65 + k] = h_t[b * DIM + kc * 64 + k];
            }
            #pragma unroll
            for (int r = 0; r < 8; ++r) {
                const int idx = r * 256 + tid;
                const int k = idx >> 5, cc = idx & 31;
                WSm[k * 33 + cc] = W[(size_t)(kc * 64 + k) * DIM + c0 + cc];
            }
            __syncthreads();
            #pragma unroll 8
            for (int k = 0; k < 64; ++k) {
                const float wv = WSm[k * 33 + c];
                #pragma unroll
                for (int bb = 0; bb < 8; ++bb)
                    acc[bb] = fmaf(hS[(bg * 8 + bb) * 65 + k], wv, acc[bb]);
            }
        }
        #pragma unroll
        for (int bb = 0; bb < 8; ++bb)
            q[(bg * 8 + bb) * DIM + c0 + c] = acc[bb];
    } else {
        const int bid = blockIdx.x - 32;        // 96 chunks: t = bid>>2, c = bid&3
        const int t = bid >> 2, c = bid & 3;
        float (*T32)[68] = (float (*)[68])sh;   // [128 k][64 j + pad]
        #pragma unroll
        for (int p = 0; p < 8; ++p) {
            const int idx = p * 256 + tid;
            const int kk = idx >> 4, s = idx & 15;
            const float4 v = *(const float4*)(Wp + (size_t)(c * 128 + kk) * K3 + t * 64 + s * 4);
            T32[kk][s * 4 + 0] = v.x; T32[kk][s * 4 + 1] = v.y;
            T32[kk][s * 4 + 2] = v.z; T32[kk][s * 4 + 3] = v.w;
        }
        __syncthreads();
        char* dst = (char*)(ws + WS_WPT) + (size_t)bid * 16384;
        #pragma unroll
        for (int p = 0; p < 4; ++p) {
            const int fid = p * 256 + tid;      // ks*256 + J*64 + lane
            const int lane = fid & 63;
            const int J = (fid >> 6) & 3;
            const int ks = fid >> 8;
            const int j = J * 16 + (lane & 15);
            const int k0 = ks * 32 + (lane >> 4) * 8;
            f4v a, b;
            a.x = T32[k0 + 0][j]; a.y = T32[k0 + 1][j];
            a.z = T32[k0 + 2][j]; a.w = T32[k0 + 3][j];
            b.x = T32[k0 + 4][j]; b.y = T32[k0 + 5][j];
            b.z = T32[k0 + 6][j]; b.w = T32[k0 + 7][j];
            *(bf16x8*)(dst + fid * 16) = pack8v(a, b);
        }
    }
}

// ------- fused one-pass attention: E (raw), Esum, C (unnormalized) -------
#define IC 16
#define NZ 8
__global__ __launch_bounds__(256) void k_attn(const float* __restrict__ h_enc,
                                              const float* __restrict__ h_dec,
                                              float* __restrict__ ws) {
    const int b = blockIdx.x, which = blockIdx.y, z = blockIdx.z;
    const int tid = threadIdx.x;
    const int n   = which ? TDEC : SRC;
    const int per = (n + NZ - 1) / NZ;
    const int i_begin = z * per;
    const int i_end = min(n, i_begin + per);
    if (i_begin >= n) return;
    const float* h  = which ? h_dec : h_enc;
    const float* q  = ws + WS_Q + which * (BS * DIM) + b * DIM;
    float* wsE      = ws + (which ? WS_EDEC : WS_EENC) + b * n;
    float* Cws      = ws + (which ? WS_CDEC : WS_CENC) + b * DIM;
    const float* hb = h + (size_t)b * DIM * n;

    __shared__ float hS[DIM * (IC + 1)];
    __shared__ float qs[DIM];
    __shared__ float Ered[256];
    __shared__ float Es[IC];

    qs[tid] = q[tid];
    qs[tid + 256] = q[tid + 256];

    const int ii = tid & (IC - 1);
    const int dg = tid >> 4;
    float c0 = 0.f, c1 = 0.f, esum = 0.f;

    for (int i0 = i_begin; i0 < i_end; i0 += IC) {
        const int ic = min(IC, i_end - i0);
        __syncthreads();
        #pragma unroll 8
        for (int idx = tid; idx < DIM * IC; idx += 256) {
            const int d = idx >> 4, i = idx & (IC - 1);
            hS[d * (IC + 1) + i] = (i < ic) ? hb[(size_t)d * n + i0 + i] : 0.f;
        }
        __syncthreads();
        float p = 0.f;
        #pragma unroll 8
        for (int d = dg * 32; d < dg * 32 + 32; ++d) p += qs[d] * hS[d * (IC + 1) + ii];
        Ered[dg * IC + ii] = p;
        __syncthreads();
        if (tid < IC) {
            float e = 0.f;
            #pragma unroll
            for (int g = 0; g < 16; ++g) e += Ered[g * IC + tid];
            Es[tid] = e;
            esum += e;
            if (tid < ic) wsE[i0 + tid] = e;
        }
        __syncthreads();
        #pragma unroll
        for (int i = 0; i < IC; ++i) {
            const float e = Es[i];
            c0 += hS[tid * (IC + 1) + i] * e;
            c1 += hS[(tid + 256) * (IC + 1) + i] * e;
        }
    }
    atomicAdd(&Cws[tid], c0);
    atomicAdd(&Cws[tid + 256], c1);
    __syncthreads();
    if (tid < IC) Ered[tid] = esum;
    __syncthreads();
    if (tid == 0) {
        float s = 0.f;
        #pragma unroll
        for (int g = 0; g < IC; ++g) s += Ered[g];
        atomicAdd(&ws[WS_ESUM + which * 64 + b], s);
    }
}

// --- ccF fragment-major c_cat, p_switch = sigmoid(W_u@c_cat+b_u), p_copy ---
__global__ void k_pswitch(const float* __restrict__ h_t,
                          const float* __restrict__ W_u,
                          const float* __restrict__ b_u,
                          float* __restrict__ out_copy,
                          float* __restrict__ ws) {
    const int b = blockIdx.x, tid = threadIdx.x;
    const float invE = 1.f / ws[WS_ESUM + b];
    const float invD = 1.f / ws[WS_ESUM + 64 + b];
    const float* Ce = ws + WS_CENC + b * DIM;
    const float* Cd = ws + WS_CDEC + b * DIM;
    ushort* ccF = (ushort*)(ws + WS_CCF);
    __shared__ float red[256];
    const int nb = b >> 4, bl = b & 15;
    float part = 0.f;
    #pragma unroll
    for (int r = 0; r < 6; ++r) {
        const int j = tid + r * 256;
        float v = (j < DIM) ? h_t[b * DIM + j]
                            : ((j < 2 * DIM) ? Ce[j - DIM] * invE : Cd[j - 2 * DIM] * invD);
        const int t = j >> 6, jj = j & 63;
        const int kc = jj >> 5, lsub = (jj >> 3) & 3, e = jj & 7;
        ccF[t * 4096 + kc * 2048 + nb * 512 + (lsub * 16 + bl) * 8 + e] = f2bf(v);
        part += W_u[j] * v;
    }
    red[tid] = part;
    __syncthreads();
    for (int s = 128; s > 0; s >>= 1) {
        if (tid < s) red[tid] += red[tid + s];
        __syncthreads();
    }
    const float ps = 1.f / (1.f + expf(-(red[0] + b_u[0])));
    if (tid == 0) ws[WS_PSW + b] = ps;
    const float* Ee = ws + WS_EENC + b * SRC;
    for (int i = tid; i < SRC; i += 256) out_copy[b * SRC + i] = ps * Ee[i] * invE;
}

// ---- MFMA fused, j-SPLIT x2: block (tile, half) computes the half-K3 partial
// logit sum for 128 vocab rows; partials stored as bf16 into the lo/hi 16 bits
// of out's f32 words (byte-disjoint, race-free). 48KB LDS -> 3 blocks/CU.
#define VB 128
#define NTILE ((NEMB + VB - 1) / VB)   // 393
#define WAITV(N) asm volatile("s_waitcnt vmcnt(" #N ")" ::: "memory")
__global__ __launch_bounds__(256, 3) void k_bigmm(const float* __restrict__ We,
                                                  const float* __restrict__ ws,
                                                  float* __restrict__ out) {
    __shared__ __align__(16) char smem[49152];  // B[2][16K] | cc 8K @32768 | T [4w][2K] @40960
    const int tile = blockIdx.x >> 1, half = blockIdx.x & 1;
    const char* wptb = (const char*)(ws + WS_WPT) + (size_t)half * 48 * 16384;
    const char* ccfb = (const char*)(ws + WS_CCF) + (size_t)half * 12 * 8192;

    const int tid  = threadIdx.x;
    const int w    = tid >> 6, lane = tid & 63;
    const int lrow = lane & 15, lgrp = lane >> 4;
    const int vw   = tile * VB + w * 32;         // wave's 32-row base
    const int row0 = vw + lrow, row1 = vw + 16 + lrow;
    char* ccL   = smem + 32768;
    char* tbase = smem + 40960 + w * 2048;
    const int swz = (lrow & 7) << 4;

    // ---- prologue: stage chunks 0,1 of this half ----
    #pragma unroll
    for (int p = 0; p < 2; ++p) {
        const char* src = wptb + (size_t)p * 16384 + tid * 16;
        char* dst = smem + p * 16384 + tid * 16;
        #pragma unroll
        for (int rnd = 0; rnd < 4; ++rnd) gl2lds16(src + rnd * 4096, dst + rnd * 4096);
    }

    // ---- load A panels once (f32 -> bf16 in-reg, nontemporal) ----
    bf16x8 A0[16], A1[16];
    if (row0 < NEMB) {
        const f4v* p = (const f4v*)(We + (size_t)row0 * DIM + lgrp * 8);
        #pragma unroll
        for (int f = 0; f < 16; ++f)
            A0[f] = pack8v(__builtin_nontemporal_load(p + f * 8),
                           __builtin_nontemporal_load(p + f * 8 + 1));
    } else {
        #pragma unroll
        for (int f = 0; f < 16; ++f) A0[f] = (bf16x8){0, 0, 0, 0, 0, 0, 0, 0};
    }
    if (row1 < NEMB) {
        const f4v* p = (const f4v*)(We + (size_t)row1 * DIM + lgrp * 8);
        #pragma unroll
        for (int f = 0; f < 16; ++f)
            A1[f] = pack8v(__builtin_nontemporal_load(p + f * 8),
                           __builtin_nontemporal_load(p + f * 8 + 1));
    } else {
        #pragma unroll
        for (int f = 0; f < 16; ++f) A1[f] = (bf16x8){0, 0, 0, 0, 0, 0, 0, 0};
    }

    f32x4 La0[4], La1[4], Ta0[4], Ta1[4];
    #pragma unroll
    for (int i = 0; i < 4; ++i) {
        La0[i] = (f32x4){0.f, 0.f, 0.f, 0.f}; La1[i] = (f32x4){0.f, 0.f, 0.f, 0.f};
        Ta0[i] = (f32x4){0.f, 0.f, 0.f, 0.f}; Ta1[i] = (f32x4){0.f, 0.f, 0.f, 0.f};
    }

    // ---- main loop: 48 chunks (12 t x 4 c), unrolled x12 ----
    // Issue/thread per 4-group: [u%4==0: cc(2), B(4)] [1: B(4)] [2: B(4)] [3: B(4)]
    // Waits (same as verified R14 table): u%4==1 -> W(6); else W(4); last chunk W(0).
    for (int it = 0; it < 4; ++it) {
        #pragma unroll
        for (int u = 0; u < 12; ++u) {
            const int i = it * 12 + u;
            if (u == 11)           { if (it == 3) { WAITV(0); } else { WAITV(4); } }
            else if ((u & 3) == 1) { WAITV(6); }
            else                   { WAITV(4); }
            __builtin_amdgcn_s_barrier();
            {
                const char* bp = smem + (u & 1) * 16384 + lane * 16;
                __builtin_amdgcn_s_setprio(1);
                #pragma unroll
                for (int ks = 0; ks < 4; ++ks) {
                    const bf16x8 b0 = *(const bf16x8*)(bp + ks * 4096);
                    const bf16x8 b1 = *(const bf16x8*)(bp + ks * 4096 + 1024);
                    const bf16x8 b2 = *(const bf16x8*)(bp + ks * 4096 + 2048);
                    const bf16x8 b3 = *(const bf16x8*)(bp + ks * 4096 + 3072);
                    Ta0[0] = __builtin_amdgcn_mfma_f32_16x16x32_bf16(A0[(u & 3) * 4 + ks], b0, Ta0[0], 0, 0, 0);
                    Ta1[0] = __builtin_amdgcn_mfma_f32_16x16x32_bf16(A1[(u & 3) * 4 + ks], b0, Ta1[0], 0, 0, 0);
                    Ta0[1] = __builtin_amdgcn_mfma_f32_16x16x32_bf16(A0[(u & 3) * 4 + ks], b1, Ta0[1], 0, 0, 0);
                    Ta1[1] = __builtin_amdgcn_mfma_f32_16x16x32_bf16(A1[(u & 3) * 4 + ks], b1, Ta1[1], 0, 0, 0);
                    Ta0[2] = __builtin_amdgcn_mfma_f32_16x16x32_bf16(A0[(u & 3) * 4 + ks], b2, Ta0[2], 0, 0, 0);
                    Ta1[2] = __builtin_amdgcn_mfma_f32_16x16x32_bf16(A1[(u & 3) * 4 + ks], b2, Ta1[2], 0, 0, 0);
                    Ta0[3] = __builtin_amdgcn_mfma_f32_16x16x32_bf16(A0[(u & 3) * 4 + ks], b3, Ta0[3], 0, 0, 0);
                    Ta1[3] = __builtin_amdgcn_mfma_f32_16x16x32_bf16(A1[(u & 3) * 4 + ks], b3, Ta1[3], 0, 0, 0);
                }
                __builtin_amdgcn_s_setprio(0);
            }
            if ((u & 3) == 3) {
                // ---- TAIL (2KB scratch, two sub-phases): cc frags once ----
                const bf16x8 c00 = *(const bf16x8*)(ccL + lane * 16);
                const bf16x8 c01 = *(const bf16x8*)(ccL + lane * 16 + 1024);
                const bf16x8 c02 = *(const bf16x8*)(ccL + lane * 16 + 2048);
                const bf16x8 c03 = *(const bf16x8*)(ccL + lane * 16 + 3072);
                const bf16x8 c10 = *(const bf16x8*)(ccL + 4096 + lane * 16);
                const bf16x8 c11 = *(const bf16x8*)(ccL + 4096 + lane * 16 + 1024);
                const bf16x8 c12 = *(const bf16x8*)(ccL + 4096 + lane * 16 + 2048);
                const bf16x8 c13 = *(const bf16x8*)(ccL + 4096 + lane * 16 + 3072);
                __builtin_amdgcn_s_setprio(1);
                // sub-phase 0: rows vw..vw+15
                #pragma unroll
                for (int nj = 0; nj < 4; ++nj) {
                    const int j = nj * 16 + lrow;
                    #pragma unroll
                    for (int r = 0; r < 4; ++r) {
                        const int v = lgrp * 4 + r;
                        *(ushort*)(tbase + v * 128 + ((j * 2) ^ ((v & 7) << 4))) =
                            f2bf(pade_tanh(Ta0[nj][r]));
                    }
                }
                {
                    const bf16x8 tfa = *(const bf16x8*)(tbase + lrow * 128 + ((lgrp * 16) ^ swz));
                    const bf16x8 tfb = *(const bf16x8*)(tbase + lrow * 128 + ((64 + lgrp * 16) ^ swz));
                    La0[0] = __builtin_amdgcn_mfma_f32_16x16x32_bf16(tfa, c00, La0[0], 0, 0, 0);
                    La0[1] = __builtin_amdgcn_mfma_f32_16x16x32_bf16(tfa, c01, La0[1], 0, 0, 0);
                    La0[2] = __builtin_amdgcn_mfma_f32_16x16x32_bf16(tfa, c02, La0[2], 0, 0, 0);
                    La0[3] = __builtin_amdgcn_mfma_f32_16x16x32_bf16(tfa, c03, La0[3], 0, 0, 0);
                    La0[0] = __builtin_amdgcn_mfma_f32_16x16x32_bf16(tfb, c10, La0[0], 0, 0, 0);
                    La0[1] = __builtin_amdgcn_mfma_f32_16x16x32_bf16(tfb, c11, La0[1], 0, 0, 0);
                    La0[2] = __builtin_amdgcn_mfma_f32_16x16x32_bf16(tfb, c12, La0[2], 0, 0, 0);
                    La0[3] = __builtin_amdgcn_mfma_f32_16x16x32_bf16(tfb, c13, La0[3], 0, 0, 0);
                }
                // sub-phase 1: rows vw+16..vw+31 (reuse scratch)
                #pragma unroll
                for (int nj = 0; nj < 4; ++nj) {
                    const int j = nj * 16 + lrow;
                    #pragma unroll
                    for (int r = 0; r < 4; ++r) {
                        const int v = lgrp * 4 + r;
                        *(ushort*)(tbase + v * 128 + ((j * 2) ^ ((v & 7) << 4))) =
                            f2bf(pade_tanh(Ta1[nj][r]));
                    }
                }
                {
                    const bf16x8 tfa = *(const bf16x8*)(tbase + lrow * 128 + ((lgrp * 16) ^ swz));
                    const bf16x8 tfb = *(const bf16x8*)(tbase + lrow * 128 + ((64 + lgrp * 16) ^ swz));
                    La1[0] = __builtin_amdgcn_mfma_f32_16x16x32_bf16(tfa, c00, La1[0], 0, 0, 0);
                    La1[1] = __builtin_amdgcn_mfma_f32_16x16x32_bf16(tfa, c01, La1[1], 0, 0, 0);
                    La1[2] = __builtin_amdgcn_mfma_f32_16x16x32_bf16(tfa, c02, La1[2], 0, 0, 0);
                    La1[3] = __builtin_amdgcn_mfma_f32_16x16x32_bf16(tfa, c03, La1[3], 0, 0, 0);
                    La1[0] = __builtin_amdgcn_mfma_f32_16x16x32_bf16(tfb, c10, La1[0], 0, 0, 0);
                    La1[1] = __builtin_amdgcn_mfma_f32_16x16x32_bf16(tfb, c11, La1[1], 0, 0, 0);
                    La1[2] = __builtin_amdgcn_mfma_f32_16x16x32_bf16(tfb, c12, La1[2], 0, 0, 0);
                    La1[3] = __builtin_amdgcn_mfma_f32_16x16x32_bf16(tfb, c13, La1[3], 0, 0, 0);
                }
                __builtin_amdgcn_s_setprio(0);
                #pragma unroll
                for (int z = 0; z < 4; ++z) {
                    Ta0[z] = (f32x4){0.f, 0.f, 0.f, 0.f};
                    Ta1[z] = (f32x4){0.f, 0.f, 0.f, 0.f};
                }
            }
            __builtin_amdgcn_s_barrier();        // all waves done with buf (u&1) / cc
            if ((u & 3) == 0) {                  // stage cc tile for this group's tail
                const int t = it * 3 + (u >> 2);
                const char* csrc = ccfb + (size_t)t * 8192 + tid * 16;
                char* cdst = ccL + tid * 16;
                gl2lds16(csrc, cdst);
                gl2lds16(csrc + 4096, cdst + 4096);
            }
            if (i + 2 < 48) {                    // refill current buffer with chunk i+2
                const char* src = wptb + (size_t)(i + 2) * 16384 + tid * 16;
                char* dst = smem + (u & 1) * 16384 + tid * 16;
                #pragma unroll
                for (int rnd = 0; rnd < 4; ++rnd)
                    gl2lds16(src + rnd * 4096, dst + rnd * 4096);
            }
        }
    }

    // ---- store: bf16 partial into lo/hi 16 bits of out's f32 word ----
    ushort* o16 = (ushort*)out;
    #pragma unroll
    for (int nb = 0; nb < 4; ++nb) {
        const int b = nb * 16 + lrow;
        #pragma unroll
        for (int r = 0; r < 4; ++r) {
            const int v0 = vw + lgrp * 4 + r;
            const int v1 = v0 + 16;
            if (v0 < NEMB) o16[((size_t)b * NEMB + v0) * 2 + half] = f2bf(La0[nb][r]);
            if (v1 < NEMB) o16[((size_t)b * NEMB + v1) * 2 + half] = f2bf(La1[nb][r]);
        }
    }
}

// -------- per-(b, quarter) softmax partial stats from packed logits --------
#define VCC 12565
__global__ void k_colstat(const float* __restrict__ out,
                          const float* __restrict__ b_out,
                          float* __restrict__ ws) {
    const int b = blockIdx.x, vc = blockIdx.y, tid = threadIdx.x;
    const unsigned* L = (const unsigned*)(out + (size_t)b * NEMB);
    const int v0 = vc * VCC, vend = min(v0 + VCC, NEMB);
    __shared__ float red[256];
    float m = -1e30f;
    for (int v = v0 + tid; v < vend; v += 256) {
        const unsigned wrd = L[v];
        m = fmaxf(m, bfdec(wrd & 0xFFFFu) + bfdec(wrd >> 16) + b_out[v]);
    }
    red[tid] = m;
    __syncthreads();
    for (int s = 128; s > 0; s >>= 1) {
        if (tid < s) red[tid] = fmaxf(red[tid], red[tid + s]);
        __syncthreads();
    }
    const float mb = red[0];
    __syncthreads();
    float sum = 0.f;
    for (int v = v0 + tid; v < vend; v += 256) {
        const unsigned wrd = L[v];
        sum += expf(bfdec(wrd & 0xFFFFu) + bfdec(wrd >> 16) + b_out[v] - mb);
    }
    red[tid] = sum;
    __syncthreads();
    for (int s = 128; s > 0; s >>= 1) {
        if (tid < s) red[tid] += red[tid + s];
        __syncthreads();
    }
    if (tid == 0) {
        ws[WS_SMAX + b * 4 + vc] = mb;
        ws[WS_SSUM + b * 4 + vc] = red[0];
    }
}

// -------- p_gen: merge 4 partials, decode packed logits, scale+exp --------
__global__ __launch_bounds__(256) void k_final(float* __restrict__ out,
                                               const float* __restrict__ b_out,
                                               const float* __restrict__ ws) {
    const int b = blockIdx.x, seg = blockIdx.y, tid = threadIdx.x;
    float m = -1e30f;
    #pragma unroll
    for (int p = 0; p < 4; ++p) m = fmaxf(m, ws[WS_SMAX + b * 4 + p]);
    float s = 0.f;
    #pragma unroll
    for (int p = 0; p < 4; ++p)
        s += ws[WS_SSUM + b * 4 + p] * expf(ws[WS_SMAX + b * 4 + p] - m);
    const float scale = (1.f - ws[WS_PSW + b]) / s;
    float* L = out + (size_t)b * NEMB;
    const int v0 = seg * 3142, vend = min(v0 + 3142, NEMB);
    for (int v = v0 + tid; v < vend; v += 256) {
        const unsigned wrd = __float_as_uint(L[v]);
        const float lg = bfdec(wrd & 0xFFFFu) + bfdec(wrd >> 16) + b_out[v];
        L[v] = expf(lg - m) * scale;
    }
}

extern "C" void kernel_launch(void* const* d_in, const int* in_sizes, int n_in,
                              void* d_out, int out_size, void* d_ws, size_t ws_size,
                              hipStream_t stream) {
    const float* h_t        = (const float*)d_in[0];
    const float* h_enc      = (const float*)d_in[1];
    const float* h_dec      = (const float*)d_in[2];
    const float* W_attn_enc = (const float*)d_in[4];
    const float* W_attn_dec = (const float*)d_in[5];
    const float* W_emb      = (const float*)d_in[6];
    const float* W_proj     = (const float*)d_in[7];
    const float* W_u        = (const float*)d_in[8];
    const float* b_u        = (const float*)d_in[9];
    const float* b_out      = (const float*)d_in[10];

    float* out = (float*)d_out;
    float* ws  = (float*)d_ws;
    float* out_copy = out + (size_t)BS * NEMB;

    k_prep   <<<128, 256, 0, stream>>>(h_t, W_attn_enc, W_attn_dec, W_proj, ws);
    k_attn   <<<dim3(64, 2, NZ), 256, 0, stream>>>(h_enc, h_dec, ws);
    k_pswitch<<<64, 256, 0, stream>>>(h_t, W_u, b_u, out_copy, ws);
    k_bigmm  <<<2 * NTILE, 256, 0, stream>>>(W_emb, ws, out);
    k_colstat<<<dim3(64, 4), 256, 0, stream>>>(out, b_out, ws);
    k_final  <<<dim3(64, 16), 256, 0, stream>>>(out, b_out, ws);
}